// Round 1
// baseline (697.487 us; speedup 1.0000x reference)
//
#include <hip/hip_runtime.h>
#include <stdint.h>

typedef __attribute__((ext_vector_type(8))) short bf16x8;
typedef __attribute__((ext_vector_type(4))) float f32x4;

__device__ __forceinline__ float b2f(short h) {
  return __uint_as_float(((unsigned)(unsigned short)h) << 16);
}
__device__ __forceinline__ short f2b(float f) {
  unsigned u = __float_as_uint(f);
  u += 0x7fffu + ((u >> 16) & 1u);
  return (short)(u >> 16);
}

// async global->LDS, 16 B per lane (global_load_lds_dwordx4)
__device__ __forceinline__ void glds16(const void* g, void* l) {
  __builtin_amdgcn_global_load_lds(
      (const __attribute__((address_space(1))) void*)g,
      (__attribute__((address_space(3))) void*)l, 16, 0, 0);
}

// XCD-aware decode: 1-D grid; the C col-tiles of one row-strip land on one XCD
// (consecutive slots), row-strips partitioned across XCDs. Bijective for
// total = 8 * RSX * C, RSX = row-strips per XCD, RPZ = row-strips per z.
__device__ __forceinline__ void xcd_decode(int C, int RSX, int RPZ,
                                           int& z, int& rowB, int& colB) {
  int id = blockIdx.x;
  int xcd = id & 7, slot = id >> 3;
  int rs = xcd * RSX + slot / C;
  colB = (slot % C) * 128;
  z = rs / RPZ;
  rowB = (rs % RPZ) * 128;
}

// ---------------- one-shot fp32 -> (bf16 hi, bf16 lo) split, 8 elem/thread ----
// Three source regions in one dispatch (grid covers n0+n1+n2 exactly, all
// multiples of 256 groups).
__global__ __launch_bounds__(256) void cvt_kernel(
    const float* __restrict__ S0, short* __restrict__ H0, short* __restrict__ L0,
    const float* __restrict__ S1, short* __restrict__ H1, short* __restrict__ L1,
    const float* __restrict__ S2, short* __restrict__ H2, short* __restrict__ L2,
    int n0, int n1, int n2) {
  int g = blockIdx.x * 256 + threadIdx.x;
  const float* s;
  short* h;
  short* l;
  if (g < n0) {
    s = S0 + (size_t)g * 8;
    h = H0 + (size_t)g * 8;
    l = L0 + (size_t)g * 8;
  } else if (g < n0 + n1) {
    size_t t = (size_t)(g - n0);
    s = S1 + t * 8;
    h = H1 + t * 8;
    l = L1 + t * 8;
  } else {
    size_t t = (size_t)(g - n0 - n1);
    s = S2 + t * 8;
    h = H2 + t * 8;
    l = L2 + t * 8;
  }
  float4 v0 = *reinterpret_cast<const float4*>(s);
  float4 v1 = *reinterpret_cast<const float4*>(s + 4);
  float vv[8] = {v0.x, v0.y, v0.z, v0.w, v1.x, v1.y, v1.z, v1.w};
  bf16x8 th, tl;
#pragma unroll
  for (int j = 0; j < 8; ++j) {
    short hh = f2b(vv[j]);
    th[j] = hh;
    tl[j] = f2b(vv[j] - b2f(hh));
  }
  *reinterpret_cast<bf16x8*>(h) = th;
  *reinterpret_cast<bf16x8*>(l) = tl;
}

// ---------------- row sums of P (bf16, 2048 cols) -> store 1/sum ----------------
__global__ __launch_bounds__(256) void rowsum_kernel(const short* __restrict__ P,
                                                     float* __restrict__ invL) {
  int wave = threadIdx.x >> 6, lane = threadIdx.x & 63;
  size_t row = (size_t)blockIdx.x * 4 + wave;
  const short* p = P + row * 2048;
  float s = 0.f;
#pragma unroll
  for (int it = 0; it < 4; ++it) {
    bf16x8 x = *reinterpret_cast<const bf16x8*>(&p[it * 512 + lane * 8]);
#pragma unroll
    for (int j = 0; j < 8; ++j) s += b2f(x[j]);
  }
#pragma unroll
  for (int m = 32; m; m >>= 1) s += __shfl_xor(s, m);
  if (lane == 0) invL[row] = 1.0f / s;
}

// =================================================================================
// projg: C = A @ B^T + bias with 3-pass split precision (ah*bh + al*bh + ah*bl),
// all operands pre-converted bf16 planes, glds staging (no staging VALU).
// One projection per dispatch (768 blocks = 8 XCD * 16 rs * 6 col).
// LO: additionally emit lo residual plane of the output.
// =================================================================================
template <bool LO>
__global__ __launch_bounds__(256) void projg_kernel(
    const short* __restrict__ Ah, const short* __restrict__ Al,
    const short* __restrict__ Bh, const short* __restrict__ Bl,
    const float* __restrict__ bias,
    short* __restrict__ Ch, short* __restrict__ Cl) {
  __shared__ alignas(16) short AsH[128 * 32];
  __shared__ alignas(16) short AsL[128 * 32];
  __shared__ alignas(16) short BsH[128 * 32];
  __shared__ alignas(16) short BsL[128 * 32];
  const int tid = threadIdx.x;
  int z, rowBase, colBase;
  xcd_decode(6, 16, 128, z, rowBase, colBase);  // total 768 = 8*16*6, z always 0
  (void)z;
  const int lane = tid & 63;
  const int ln = lane & 15;
  const int qd = lane >> 4;
  const int w = tid >> 6;
  const int wr = w >> 1, wc = w & 1;

  f32x4 acc[4][4];
#pragma unroll
  for (int i = 0; i < 4; ++i)
#pragma unroll
    for (int j = 0; j < 4; ++j) acc[i][j] = 0.f;

  for (int kb = 0; kb < 768; kb += 32) {
#pragma unroll
    for (int q = 0; q < 2; ++q) {
      int c = q * 256 + tid;
      int r = c >> 2;
      int k0 = (c & 3) << 3;
      size_t ao = (size_t)(rowBase + r) * 768 + kb + k0;
      size_t bo = (size_t)(colBase + r) * 768 + kb + k0;
      glds16(&Ah[ao], &AsH[c * 8]);
      glds16(&Al[ao], &AsL[c * 8]);
      glds16(&Bh[bo], &BsH[c * 8]);
      glds16(&Bl[bo], &BsL[c * 8]);
    }
    __syncthreads();
    bf16x8 ah[4], bh[4], t[4];
#pragma unroll
    for (int rt = 0; rt < 4; ++rt)
      ah[rt] = *reinterpret_cast<const bf16x8*>(&AsH[(wr * 64 + rt * 16 + ln) * 32 + qd * 8]);
#pragma unroll
    for (int ct = 0; ct < 4; ++ct)
      bh[ct] = *reinterpret_cast<const bf16x8*>(&BsH[(wc * 64 + ct * 16 + ln) * 32 + qd * 8]);
#pragma unroll
    for (int rt = 0; rt < 4; ++rt)
#pragma unroll
      for (int ct = 0; ct < 4; ++ct)
        acc[rt][ct] = __builtin_amdgcn_mfma_f32_16x16x32_bf16(ah[rt], bh[ct], acc[rt][ct], 0, 0, 0);
#pragma unroll
    for (int rt = 0; rt < 4; ++rt)
      t[rt] = *reinterpret_cast<const bf16x8*>(&AsL[(wr * 64 + rt * 16 + ln) * 32 + qd * 8]);
#pragma unroll
    for (int rt = 0; rt < 4; ++rt)
#pragma unroll
      for (int ct = 0; ct < 4; ++ct)
        acc[rt][ct] = __builtin_amdgcn_mfma_f32_16x16x32_bf16(t[rt], bh[ct], acc[rt][ct], 0, 0, 0);
#pragma unroll
    for (int ct = 0; ct < 4; ++ct)
      t[ct] = *reinterpret_cast<const bf16x8*>(&BsL[(wc * 64 + ct * 16 + ln) * 32 + qd * 8]);
#pragma unroll
    for (int rt = 0; rt < 4; ++rt)
#pragma unroll
      for (int ct = 0; ct < 4; ++ct)
        acc[rt][ct] = __builtin_amdgcn_mfma_f32_16x16x32_bf16(ah[rt], t[ct], acc[rt][ct], 0, 0, 0);
    __syncthreads();
  }

#pragma unroll
  for (int rt = 0; rt < 4; ++rt) {
    int row0 = rowBase + wr * 64 + rt * 16 + qd * 4;
#pragma unroll
    for (int ct = 0; ct < 4; ++ct) {
      int col = colBase + wc * 64 + ct * 16 + ln;
      float bb = bias[col];
      f32x4 a = acc[rt][ct];
#pragma unroll
      for (int r = 0; r < 4; ++r) {
        float val = a[r] + bb;
        short h = f2b(val);
        Ch[(size_t)(row0 + r) * 768 + col] = h;
        if constexpr (LO) Cl[(size_t)(row0 + r) * 768 + col] = f2b(val - b2f(h));
      }
    }
  }
}

// =================================================================================
// sim2: P = exp(vp_hi*(lp_hi+lp_lo)^T - 20), fused 2 products per K-tile.
// glds staging, plain LDS layout.
// =================================================================================
__global__ __launch_bounds__(256) void sim2_kernel(const short* __restrict__ vp,
                                                   const short* __restrict__ lph,
                                                   const short* __restrict__ lpl,
                                                   short* __restrict__ P) {
  __shared__ alignas(16) short As[128 * 32];
  __shared__ alignas(16) short Bh[128 * 32];
  __shared__ alignas(16) short Bl[128 * 32];
  const int tid = threadIdx.x;
  int z, rowBase, colBase;
  xcd_decode(16, 16, 16, z, rowBase, colBase);  // total 2048 = 8*16*16
  const short* Az = vp + (size_t)z * 2048 * 768;
  const short* B0 = lph + (size_t)z * 2048 * 768;
  const short* B1 = lpl + (size_t)z * 2048 * 768;
  const int lane = tid & 63;
  const int ln = lane & 15;
  const int qd = lane >> 4;
  const int w = tid >> 6;
  const int wr = w >> 1, wc = w & 1;

  f32x4 acc[4][4];
#pragma unroll
  for (int i = 0; i < 4; ++i)
#pragma unroll
    for (int j = 0; j < 4; ++j) acc[i][j] = 0.f;

  for (int kb = 0; kb < 768; kb += 32) {
#pragma unroll
    for (int q = 0; q < 2; ++q) {
      int c = q * 256 + tid;
      int r = c >> 2;
      int k0 = (c & 3) << 3;
      glds16(&Az[(size_t)(rowBase + r) * 768 + kb + k0], &As[c * 8]);
      glds16(&B0[(size_t)(colBase + r) * 768 + kb + k0], &Bh[c * 8]);
      glds16(&B1[(size_t)(colBase + r) * 768 + kb + k0], &Bl[c * 8]);
    }
    __syncthreads();
    bf16x8 af[4], bf[4];
#pragma unroll
    for (int rt = 0; rt < 4; ++rt)
      af[rt] = *reinterpret_cast<const bf16x8*>(&As[(wr * 64 + rt * 16 + ln) * 32 + qd * 8]);
#pragma unroll
    for (int ct = 0; ct < 4; ++ct)
      bf[ct] = *reinterpret_cast<const bf16x8*>(&Bh[(wc * 64 + ct * 16 + ln) * 32 + qd * 8]);
#pragma unroll
    for (int rt = 0; rt < 4; ++rt)
#pragma unroll
      for (int ct = 0; ct < 4; ++ct)
        acc[rt][ct] = __builtin_amdgcn_mfma_f32_16x16x32_bf16(af[rt], bf[ct], acc[rt][ct], 0, 0, 0);
#pragma unroll
    for (int ct = 0; ct < 4; ++ct)
      bf[ct] = *reinterpret_cast<const bf16x8*>(&Bl[(wc * 64 + ct * 16 + ln) * 32 + qd * 8]);
#pragma unroll
    for (int rt = 0; rt < 4; ++rt)
#pragma unroll
      for (int ct = 0; ct < 4; ++ct)
        acc[rt][ct] = __builtin_amdgcn_mfma_f32_16x16x32_bf16(af[rt], bf[ct], acc[rt][ct], 0, 0, 0);
    __syncthreads();
  }

  short* Pz = P + (size_t)z * 2048 * 2048;
#pragma unroll
  for (int rt = 0; rt < 4; ++rt) {
    int row0 = rowBase + wr * 64 + rt * 16 + qd * 4;
#pragma unroll
    for (int ct = 0; ct < 4; ++ct) {
      int col = colBase + wc * 64 + ct * 16 + ln;
      f32x4 a = acc[rt][ct];
#pragma unroll
      for (int r = 0; r < 4; ++r)
        Pz[(size_t)(row0 + r) * 2048 + col] = f2b(__expf(a[r] - 20.0f));
    }
  }
}

// =================================================================================
// gemm_k: C[m,n] = sum_k A[m,k]*B[n,k], plain bf16. Plain operands via glds.
// TA/TB: operand given as [K,M]/[K,N] -> register-transpose staging (swizzled).
// SB: scale B by invL[k]. BF32: B fp32. DUALA: A split 768|768.
// MODE 2: bf16 = acc*invL[row]; MODE 3: bf16 = acc; MODE 4: fp32 = acc+bias[col]
// =================================================================================
template <int MODE, bool TA, bool TB, bool SB, bool BF32, bool DUALA>
__global__ __launch_bounds__(256) void gemm_k(const short* __restrict__ A,
                                              const short* __restrict__ A2,
                                              const void* __restrict__ B,
                                              void* __restrict__ C,
                                              const float* __restrict__ bias,
                                              const float* __restrict__ invL,
                                              int C_, int RSX_, int RPZ_,
                                              int K, int ldA, int ldB, int ldC,
                                              long sA, long sB, long sC, long sL) {
  __shared__ alignas(16) short As[128 * 32];
  __shared__ alignas(16) short Bs[128 * 32];
  const int tid = threadIdx.x;
  int z, rowBase, colBase;
  xcd_decode(C_, RSX_, RPZ_, z, rowBase, colBase);
  const short* Az = A + (size_t)z * sA;
  const float* Lz = invL ? (invL + (size_t)z * sL) : nullptr;
  const int lane = tid & 63;
  const int ln = lane & 15;
  const int qd = lane >> 4;
  const int w = tid >> 6;
  const int wr = w >> 1, wc = w & 1;
  constexpr bool GA = !TA;
  constexpr bool GB = !TB && !BF32;

  f32x4 acc[4][4];
#pragma unroll
  for (int i = 0; i < 4; ++i)
#pragma unroll
    for (int j = 0; j < 4; ++j) acc[i][j] = 0.f;

  for (int kb = 0; kb < K; kb += 32) {
    if constexpr (GA) {
#pragma unroll
      for (int q = 0; q < 2; ++q) {
        int c = q * 256 + tid;
        int r = c >> 2;
        int k0 = (c & 3) << 3;
        int kk = kb + k0;
        const short* src;
        if constexpr (DUALA) {
          src = (kk < 768) ? &Az[(size_t)(rowBase + r) * 768 + kk]
                           : &A2[(size_t)(rowBase + r) * 768 + kk - 768];
        } else {
          src = &Az[(size_t)(rowBase + r) * ldA + kk];
        }
        glds16(src, &As[c * 8]);
      }
    } else {
#pragma unroll
      for (int q = 0; q < 2; ++q) {
        int task = q * 256 + tid;
        int m = task & 127;
        int kc = (task >> 7) << 3;
        bf16x8 t;
#pragma unroll
        for (int s = 0; s < 8; ++s)
          t[s] = Az[(size_t)(kb + kc + s) * ldA + rowBase + m];
        *reinterpret_cast<bf16x8*>(&As[m * 32 + (kc ^ ((m & 3) << 3))]) = t;
      }
    }
    if constexpr (TB) {
      const short* Bz = (const short*)B + (size_t)z * sB;
#pragma unroll
      for (int q = 0; q < 2; ++q) {
        int task = q * 256 + tid;
        int n = task & 127;
        int kc = (task >> 7) << 3;
        bf16x8 t;
#pragma unroll
        for (int s = 0; s < 8; ++s) {
          short v = Bz[(size_t)(kb + kc + s) * ldB + colBase + n];
          if constexpr (SB) v = f2b(b2f(v) * Lz[kb + kc + s]);
          t[s] = v;
        }
        *reinterpret_cast<bf16x8*>(&Bs[n * 32 + (kc ^ ((n & 3) << 3))]) = t;
      }
    } else if constexpr (BF32) {
      const float* Bf = (const float*)B + (size_t)z * sB;
#pragma unroll
      for (int q = 0; q < 2; ++q) {
        int c = q * 256 + tid;
        int r = c >> 2;
        int k0 = (c & 3) << 3;
        const float* p = &Bf[(size_t)(colBase + r) * ldB + kb + k0];
        float4 v0 = *reinterpret_cast<const float4*>(p);
        float4 v1 = *reinterpret_cast<const float4*>(p + 4);
        float vv[8] = {v0.x, v0.y, v0.z, v0.w, v1.x, v1.y, v1.z, v1.w};
        bf16x8 t;
#pragma unroll
        for (int s = 0; s < 8; ++s) t[s] = f2b(vv[s]);
        *reinterpret_cast<bf16x8*>(&Bs[r * 32 + (k0 ^ ((r & 3) << 3))]) = t;
      }
    } else {
      const short* Bz = (const short*)B + (size_t)z * sB;
#pragma unroll
      for (int q = 0; q < 2; ++q) {
        int c = q * 256 + tid;
        int r = c >> 2;
        int k0 = (c & 3) << 3;
        glds16(&Bz[(size_t)(colBase + r) * ldB + kb + k0], &Bs[c * 8]);
      }
    }
    __syncthreads();
    bf16x8 af[4], bfv[4];
#pragma unroll
    for (int rt = 0; rt < 4; ++rt) {
      int m = wr * 64 + rt * 16 + ln;
      int off = GA ? (qd * 8) : ((qd * 8) ^ ((m & 3) << 3));
      af[rt] = *reinterpret_cast<const bf16x8*>(&As[m * 32 + off]);
    }
#pragma unroll
    for (int ct = 0; ct < 4; ++ct) {
      int n = wc * 64 + ct * 16 + ln;
      int off = GB ? (qd * 8) : ((qd * 8) ^ ((n & 3) << 3));
      bfv[ct] = *reinterpret_cast<const bf16x8*>(&Bs[n * 32 + off]);
    }
#pragma unroll
    for (int rt = 0; rt < 4; ++rt)
#pragma unroll
      for (int ct = 0; ct < 4; ++ct)
        acc[rt][ct] =
            __builtin_amdgcn_mfma_f32_16x16x32_bf16(af[rt], bfv[ct], acc[rt][ct], 0, 0, 0);
    __syncthreads();
  }

#pragma unroll
  for (int rt = 0; rt < 4; ++rt) {
    int row0 = rowBase + wr * 64 + rt * 16 + qd * 4;
#pragma unroll
    for (int ct = 0; ct < 4; ++ct) {
      int col = colBase + wc * 64 + ct * 16 + ln;
      f32x4 a = acc[rt][ct];
      if constexpr (MODE == 2) {
        short* Co = (short*)C + (size_t)z * sC;
#pragma unroll
        for (int r = 0; r < 4; ++r)
          Co[(size_t)(row0 + r) * ldC + col] = f2b(a[r] * Lz[row0 + r]);
      } else if constexpr (MODE == 3) {
        short* Co = (short*)C + (size_t)z * sC;
#pragma unroll
        for (int r = 0; r < 4; ++r) Co[(size_t)(row0 + r) * ldC + col] = f2b(a[r]);
      } else {  // MODE 4
        float* Co = (float*)C + (size_t)z * sC;
        float bb = bias[col];
#pragma unroll
        for (int r = 0; r < 4; ++r) Co[(size_t)(row0 + r) * ldC + col] = a[r] + bb;
      }
    }
  }
}

extern "C" void kernel_launch(void* const* d_in, const int* in_sizes, int n_in,
                              void* d_out, int out_size, void* d_ws, size_t ws_size,
                              hipStream_t stream) {
  const float* vf = (const float*)d_in[0];
  const float* lf = (const float*)d_in[1];
  const float* Wv = (const float*)d_in[2];
  const float* bv = (const float*)d_in[3];
  const float* Wl = (const float*)d_in[4];
  const float* bl = (const float*)d_in[5];
  const float* Wo = (const float*)d_in[6];
  const float* bo = (const float*)d_in[7];

  constexpr int Bz = 8, L = 2048, D = 768, M = Bz * L, D2 = 2 * D;
  constexpr size_t PLANE = (size_t)M * D;      // 12,582,912 elems
  constexpr size_t WPLANE = (size_t)D * D;     // 589,824 elems

  char* wp = (char*)d_ws;
  auto alloc = [&](size_t bytes) {
    char* p = wp;
    wp += (bytes + 255) & ~(size_t)255;
    return p;
  };
  short* vp_hi = (short*)alloc(PLANE * 2);               // 25.2 MB; -> al after av
  short* P     = (short*)alloc((size_t)Bz * L * L * 2);  // 67.1 MB; -> out_tmp after al
  float* invL  = (float*)alloc((size_t)M * 4);           // 64 KB
  short* al      = vp_hi;
  float* out_tmp = (float*)P;

  short* lp_hi = (short*)d_out;
  short* lp_lo = lp_hi + PLANE;
  short* av    = lp_lo;  // lp_lo dead after sim

  // Transient hi/lo planes live inside the (not-yet-written) P region:
  // fh/fl (feature, 50.3 MB) + 4 weight planes (4.7 MB) = 55.0 MB <= 67.1 MB.
  short* fh  = P;
  short* fl  = P + PLANE;
  short* wvh = P + 2 * PLANE;
  short* wvl = wvh + WPLANE;
  short* wlh = wvl + WPLANE;
  short* wll = wlh + WPLANE;

  constexpr int GF = (int)(PLANE / 8);   // 1,572,864 groups (feature)
  constexpr int GW = (int)(WPLANE / 8);  // 73,728 groups (weight)

  // 1a) convert vision features + both weights (one-shot hi/lo split)
  cvt_kernel<<<dim3((GF + 2 * GW) / 256), 256, 0, stream>>>(
      vf, fh, fl, Wv, wvh, wvl, Wl, wlh, wll, GF, GW, GW);

  // 1b) vision projection: vp_hi = round(Vf @ Wv^T + bv). 768 blocks = 8*16*6
  projg_kernel<false><<<dim3(768), 256, 0, stream>>>(fh, fl, wvh, wvl, bv, vp_hi, nullptr);

  // 1c) convert language features (reuse the same planes)
  cvt_kernel<<<dim3(GF / 256), 256, 0, stream>>>(
      lf, fh, fl, nullptr, nullptr, nullptr, nullptr, nullptr, nullptr, GF, 0, 0);

  // 1d) language projection: lp_hi + lp_lo = split(Lf @ Wl^T + bl)
  projg_kernel<true><<<dim3(768), 256, 0, stream>>>(fh, fl, wlh, wll, bl, lp_hi, lp_lo);

  // 2) P = exp(vp*lp^T - 20). 2048 blocks = 8 * 16 * 16 (overwrites planes)
  sim2_kernel<<<dim3(2048), 256, 0, stream>>>(vp_hi, lp_hi, lp_lo, P);

  // 3) invL
  rowsum_kernel<<<dim3(M / 4), 256, 0, stream>>>(P, invL);

  // 4) aligned_vision = (P @ vp) * invL[row] -> av.  768 blocks = 8 * 16 * 6
  gemm_k<2, false, true, false, false, false><<<dim3(768), 256, 0, stream>>>(
      P, nullptr, vp_hi, av, nullptr, invL, 6, 16, 16, L, L, D, D,
      (long)L * L, (long)L * D, (long)L * D, (long)L);

  // 5) aligned_language = P^T @ (lp * invL[k]) -> al.  768 blocks
  gemm_k<3, true, true, true, false, false><<<dim3(768), 256, 0, stream>>>(
      P, nullptr, lp_hi, al, nullptr, invL, 6, 16, 16, L, L, D, D,
      (long)L * L, (long)L * D, (long)L * D, (long)L);

  // 6) out = [av | al] @ Wo^T + bo -> out_tmp (fp32). 768 blocks = 8 * 16 * 6, z=0
  gemm_k<4, false, false, false, true, true><<<dim3(768), 256, 0, stream>>>(
      av, al, Wo, out_tmp, bo, nullptr, 6, 16, 128, D2, D, D2, D, 0, 0, 0, 0);

  // 7) out_tmp -> d_out
  hipMemcpyAsync(d_out, out_tmp, (size_t)M * D * 4, hipMemcpyDeviceToDevice, stream);
}